// Round 9
// baseline (6137.491 us; speedup 1.0000x reference)
//
#include <hip/hip_runtime.h>

// Stacked 2-layer tanh RNN, SEQ=512, B=64, IN=H=1024.
// Round 9: INSTRUMENTED round on the R8 base (proven sync + data paths).
//  S1 detect->VALUBusy: pollers busy-spin with ILP-4 v_fmac burn (no s_sleep).
//  S2 poll-iters->FETCH: lane0 fetches a unique cold 64B line per poll iter
//     from a dead d_ws stripe (guarded by ws_size).
//  S3 publish-visibility->LDS_BANK_CONFLICT: wave0 reads back its own LLC
//     flag after publishing; each miss fires an 8-read 64-way bank-conflict
//     burst (<=24 iters).
//  Real opts: publish BEFORE Y stores (Y off serial chain); prefetch
//  keep-alive moved to next loop-top (retire stall off B2 path).

typedef unsigned short ushort_t;
typedef unsigned int uint32;
typedef __attribute__((ext_vector_type(4))) int i32x4;
typedef __attribute__((ext_vector_type(4))) unsigned int u32x4;
typedef __attribute__((ext_vector_type(4))) float f32x4;
typedef __attribute__((ext_vector_type(8))) __bf16 bfrag;

__device__ __forceinline__ f32x4 mfma_bf16(u32x4 a, u32x4 b, f32x4 c) {
  return __builtin_amdgcn_mfma_f32_16x16x32_bf16(
      __builtin_bit_cast(bfrag, a), __builtin_bit_cast(bfrag, b), c, 0, 0, 0);
}

__device__ __forceinline__ uint32 bf16rne(float f) {
  uint32 u = __builtin_bit_cast(uint32, f);
  return (u + 0x7fffu + ((u >> 16) & 1u)) >> 16;
}

__device__ __forceinline__ uint32 cvt_pk(float lo, float hi) {
  uint32 r;
  asm("v_cvt_pk_bf16_f32 %0, %1, %2" : "=v"(r) : "v"(lo), "v"(hi));
  return r;
}
__device__ __forceinline__ u32x4 pack8(f32x4 a, f32x4 b) {
  u32x4 r;
  r.x = cvt_pk(a.x, a.y);
  r.y = cvt_pk(a.z, a.w);
  r.z = cvt_pk(b.x, b.y);
  r.w = cvt_pk(b.z, b.w);
  return r;
}

template <int BOFF>
__device__ __forceinline__ void ld16(u32x4& d, const ushort_t* base) {
  asm volatile("global_load_dwordx4 %0, %1, off offset:%c2 sc0"
               : "=v"(d) : "v"(base), "i"(BOFF) : "memory");
}

#define LOADB(BUF, AP, KOFF)                 \
  ld16<(KOFF) * 2 + 0>(BUF[0], AP);          \
  ld16<(KOFF) * 2 + 64>(BUF[1], AP);         \
  ld16<(KOFF) * 2 + 128>(BUF[2], AP);        \
  ld16<(KOFF) * 2 + 192>(BUF[3], AP);        \
  ld16<(KOFF) * 2 + 256>(BUF[4], AP);        \
  ld16<(KOFF) * 2 + 320>(BUF[5], AP);        \
  ld16<(KOFF) * 2 + 384>(BUF[6], AP);        \
  ld16<(KOFF) * 2 + 448>(BUF[7], AP);

// ILP-4 VALU burn: 32 v_fmac, ~1 issue/cycle (S1 signal).
#define VBURN(B0_, B1_, B2_, B3_, K_)                                   \
  asm volatile(                                                         \
      "v_fmac_f32 %0, %4, %4\n\tv_fmac_f32 %1, %4, %4\n\t"              \
      "v_fmac_f32 %2, %4, %4\n\tv_fmac_f32 %3, %4, %4\n\t"              \
      "v_fmac_f32 %0, %4, %4\n\tv_fmac_f32 %1, %4, %4\n\t"              \
      "v_fmac_f32 %2, %4, %4\n\tv_fmac_f32 %3, %4, %4\n\t"              \
      "v_fmac_f32 %0, %4, %4\n\tv_fmac_f32 %1, %4, %4\n\t"              \
      "v_fmac_f32 %2, %4, %4\n\tv_fmac_f32 %3, %4, %4\n\t"              \
      "v_fmac_f32 %0, %4, %4\n\tv_fmac_f32 %1, %4, %4\n\t"              \
      "v_fmac_f32 %2, %4, %4\n\tv_fmac_f32 %3, %4, %4\n\t"              \
      "v_fmac_f32 %0, %4, %4\n\tv_fmac_f32 %1, %4, %4\n\t"              \
      "v_fmac_f32 %2, %4, %4\n\tv_fmac_f32 %3, %4, %4\n\t"              \
      "v_fmac_f32 %0, %4, %4\n\tv_fmac_f32 %1, %4, %4\n\t"              \
      "v_fmac_f32 %2, %4, %4\n\tv_fmac_f32 %3, %4, %4\n\t"              \
      "v_fmac_f32 %0, %4, %4\n\tv_fmac_f32 %1, %4, %4\n\t"              \
      "v_fmac_f32 %2, %4, %4\n\tv_fmac_f32 %3, %4, %4\n\t"              \
      "v_fmac_f32 %0, %4, %4\n\tv_fmac_f32 %1, %4, %4\n\t"              \
      "v_fmac_f32 %2, %4, %4\n\tv_fmac_f32 %3, %4, %4"                  \
      : "+v"(B0_), "+v"(B1_), "+v"(B2_), "+v"(B3_) : "v"(K_))

__device__ __forceinline__ int line_min16(const int* p, int doInv) {
  i32x4 q0, q1, q2, q3;
  if (doInv) asm volatile("s_dcache_inv" ::: "memory");
  asm volatile(
      "s_load_dwordx4 %0, %4, 0x0\n\t"
      "s_load_dwordx4 %1, %4, 0x10\n\t"
      "s_load_dwordx4 %2, %4, 0x20\n\t"
      "s_load_dwordx4 %3, %4, 0x30\n\t"
      "s_waitcnt lgkmcnt(0)"
      : "=s"(q0), "=s"(q1), "=s"(q2), "=s"(q3)
      : "s"(p) : "memory");
  int m = min(min(q0.x, q0.y), min(q0.z, q0.w));
  m = min(m, min(min(q1.x, q1.y), min(q1.z, q1.w)));
  m = min(m, min(min(q2.x, q2.y), min(q2.z, q2.w)));
  m = min(m, min(min(q3.x, q3.y), min(q3.z, q3.w)));
  return m;
}

__global__ void rnn_init(int* c) {
  for (int k = threadIdx.x; k < 8193; k += 256) {
    int z = 0;
    asm volatile("global_store_dword %0, %1, off sc0 sc1"
                 :: "v"(c + k), "v"(z) : "memory");
  }
  asm volatile("s_waitcnt vmcnt(0)" ::: "memory");
}

__global__ __launch_bounds__(512) void rnn_main(
    const float* __restrict__ Xt, const float* __restrict__ W0,
    const float* __restrict__ b0, const float* __restrict__ W1,
    const float* __restrict__ b1, float* __restrict__ Y,
    ushort_t* hbuf, int* cnt, char* burnR) {
  __shared__ float part[2][4][16][17];
  __shared__ int s_slot;

  const int tid = threadIdx.x;
  const int wave = tid >> 6;
  const int lane = tid & 63;
  const int ln15 = lane & 15;
  const int lq = lane >> 4;
  const int n = wave & 3;
  const bool fin = wave < 4;

  uint32 xcc;
  asm("s_getreg_b32 %0, hwreg(HW_REG_XCC_ID)" : "=s"(xcc));
  const int xcd = xcc & 7;

  int* fbase  = cnt + xcd * 1024;
  int* abortp = cnt + 8192;

  if (tid == 0) {
    int one = 1, old;
    asm volatile("global_atomic_add %0, %1, %2, off sc0 sc1\n\ts_waitcnt vmcnt(0)"
                 : "=v"(old) : "v"(fbase), "v"(one) : "memory");
    s_slot = old & 31;
  }
  __syncthreads();
  const int slot = s_slot;
  const bool isL1 = slot >= 16;
  const int F0 = (slot & 15) * 64;
  const int fcol = F0 + n * 16 + ln15;
  const int row8 = ln15 & 7;

  const int* fl0p = fbase + 896;
  const int* fl1p = fbase + 912;
  int* fastflag = fbase + (isL1 ? 912 : 896) + (slot & 15);

  const int* myf = (lane < 16) ? (fbase + 16 + ln15 * 16)
                  : (lane < 32) ? (fbase + 528 + ln15 * 16)
                                : (fbase + 16);
  int* slowflag = fbase + (isL1 ? 528 : 16) + (slot & 15) * 16;

  if ((slot & 15) == 0 && tid < 16) {
    int z = 0;
    asm volatile("global_store_dword %0, %1, off sc0"
                 :: "v"((int*)(fbase + (isL1 ? 912 : 896) + tid)), "v"(z) : "memory");
  }

  // S2 burn stripe: 256KB per poller id.
  char* stripe = burnR ? burnR + (size_t)(xcd * 32 + slot) * 262144 : (char*)0;
  uint32 junk = 0;
  // S1 burn accumulators (opaque).
  float sb0 = (float)tid, sb1 = sb0 + 1.f, sb2 = sb0 + 2.f, sb3 = sb0 + 3.f;
  const float sbk = 1.0000001f;

  const int kh = isL1 ? (fin ? 0 : 1) : (fin ? 1 : 0);
  const float* Wsrc = isL1 ? W1 : W0;

  u32x4 bw[32];
  {
    const float* wp = Wsrc + (size_t)fcol * 2048 + kh * 1024 + lq * 8;
#pragma unroll
    for (int j = 0; j < 32; ++j) {
      f32x4 w0 = *(const f32x4*)(wp + j * 32);
      f32x4 w1 = *(const f32x4*)(wp + j * 32 + 4);
      bw[j] = pack8(w0, w1);
    }
  }
  const float bia = fin ? (isL1 ? b1 : b0)[fcol] : 0.f;

  ushort_t* h0b = hbuf + (size_t)xcd * 40960;
  ushort_t* h1b = h0b + 24576;

  auto gemm_h = [&](const ushort_t* hsrc) -> f32x4 {
    f32x4 a = {0.f, 0.f, 0.f, 0.f};
    const ushort_t* ap = hsrc + row8 * 1024 + lq * 8;
    u32x4 fa[8], fb[8];
    LOADB(fa, ap, 0);
    LOADB(fb, ap, 256);
    asm volatile("s_waitcnt vmcnt(8)" ::: "memory");
    __builtin_amdgcn_sched_barrier(0);
#pragma unroll
    for (int j = 0; j < 8; ++j) a = mfma_bf16(fa[j], bw[j], a);
    LOADB(fa, ap, 512);
    asm volatile("s_waitcnt vmcnt(8)" ::: "memory");
    __builtin_amdgcn_sched_barrier(0);
#pragma unroll
    for (int j = 0; j < 8; ++j) a = mfma_bf16(fb[j], bw[8 + j], a);
    LOADB(fb, ap, 768);
    asm volatile("s_waitcnt vmcnt(8)" ::: "memory");
    __builtin_amdgcn_sched_barrier(0);
#pragma unroll
    for (int j = 0; j < 8; ++j) a = mfma_bf16(fa[j], bw[16 + j], a);
    asm volatile("s_waitcnt vmcnt(0)" ::: "memory");
    __builtin_amdgcn_sched_barrier(0);
#pragma unroll
    for (int j = 0; j < 8; ++j) a = mfma_bf16(fb[j], bw[24 + j], a);
    return a;
  };

  auto gemm_x = [&](int t) -> f32x4 {
    f32x4 a = {0.f, 0.f, 0.f, 0.f};
    const float* xp = Xt + ((size_t)t * 64 + xcd * 8 + row8) * 1024 + lq * 8;
#pragma unroll
    for (int j = 0; j < 32; ++j) {
      f32x4 x0 = *(const f32x4*)(xp + j * 32);
      f32x4 x1 = *(const f32x4*)(xp + j * 32 + 4);
      a = mfma_bf16(pack8(x0, x1), bw[j], a);
    }
    return a;
  };

  int mode = 0;
  uint32 pf0 = 0, pf1 = 0;

  for (int t = 0; t < 512; ++t) {
    const int buf = t & 1;
    f32x4 acc = {0.f, 0.f, 0.f, 0.f};

    if (wave == 0) {
      const int tA = isL1 ? t + 1 : t;
      const int tB = isL1 ? t : t - 2;
      const bool needA = tA >= 1, needB = tB >= 1;
      const bool eligA = needA && tA >= 2 && !mode;
      const bool eligB = needB && tB >= 2 && !mode;
      bool fastDone = false;
      if (eligA || eligB) {
        for (int it = 0; it < 512; ++it) {
          int mA = line_min16(fl0p, 1);
          int mB = line_min16(fl1p, 0);
          if ((!eligA || mA >= tA) && (!eligB || mB >= tB)) { fastDone = true; break; }
          if (stripe && lane == 0 && it < 4096)
            asm volatile("global_load_dword %0, %1, off\n\ts_waitcnt vmcnt(0)"
                         : "=v"(junk) : "v"(stripe + ((it & 4095) << 6)) : "memory");
          VBURN(sb0, sb1, sb2, sb3, sbk);
        }
        if (!fastDone) mode = 1;
      }
      const bool llcA = needA && (!eligA || !fastDone);
      const bool llcB = needB && (!eligB || !fastDone);
      if (llcA || llcB) {
        const int tgt = (lane < 16) ? (llcA ? tA : (int)0x80000000)
                       : (lane < 32) ? (llcB ? tB : (int)0x80000000)
                                     : (int)0x80000000;
        for (int it = 0;; ++it) {
          int v;
          asm volatile("global_load_dword %0, %1, off sc0 sc1\n\ts_waitcnt vmcnt(0)"
                       : "=v"(v) : "v"(myf) : "memory");
          if (__all(v >= tgt)) break;
          if (stripe && lane == 0 && it < 4096)
            asm volatile("global_load_dword %0, %1, off\n\ts_waitcnt vmcnt(0)"
                         : "=v"(junk) : "v"(stripe + ((it & 4095) << 6)) : "memory");
          VBURN(sb0, sb1, sb2, sb3, sbk);
          if ((it & 255) == 255) {
            int a;
            asm volatile("global_load_dword %0, %1, off sc0 sc1\n\ts_waitcnt vmcnt(0)"
                         : "=v"(a) : "v"(abortp) : "memory");
            if (a) break;
            if (it > (1 << 18)) {
              int one = 1;
              asm volatile("global_store_dword %0, %1, off sc0 sc1\n\ts_waitcnt vmcnt(0)"
                           :: "v"(abortp), "v"(one) : "memory");
              break;
            }
          }
        }
      }
    } else if (!isL1 && !fin) {
      asm volatile("" :: "v"(pf0), "v"(pf1));  // retire prev prefetch (off-path)
      {
        int tn = t < 511 ? t + 1 : 511;
        const char* pfp = (const char*)(Xt + ((size_t)tn * 64 + xcd * 8) * 1024)
                          + n * 8192 + lane * 128;
        asm volatile("global_load_dword %0, %1, off" : "=v"(pf0) : "v"(pfp));
        asm volatile("global_load_dword %0, %1, off offset:64" : "=v"(pf1) : "v"(pfp));
      }
      acc = gemm_x(t);
#pragma unroll
      for (int r = 0; r < 4; ++r) part[buf][n][lq * 4 + r][ln15] = acc[r];
    }
    __syncthreads();  // B0

    if (!isL1) {
      if (fin && t >= 1) acc = gemm_h(h0b + ((t - 1) % 3) * 8192);
    } else {
      if (fin) {
        acc = gemm_h(h0b + (t % 3) * 8192);
      } else {
        if (t >= 1) acc = gemm_h(h1b + ((t - 1) & 1) * 8192);
#pragma unroll
        for (int r = 0; r < 4; ++r) part[buf][n][lq * 4 + r][ln15] = acc[r];
      }
    }
    __syncthreads();  // B1

    float o[4];
    if (fin) {
#pragma unroll
      for (int r = 0; r < 4; ++r) {
        float s = acc[r] + part[buf][n][lq * 4 + r][ln15] + bia;
        float ax = fabsf(s);
        float e = __expf(2.f * ax);
        float rr = 1.f - 2.f * __builtin_amdgcn_rcpf(e + 1.f);
        o[r] = copysignf(rr, s);
      }
      if (lq < 2) {  // h stores only (Y moved after publish)
        ushort_t* hd = (isL1 ? h1b + (t & 1) * 8192 : h0b + (t % 3) * 8192)
                       + (lq * 4) * 1024 + fcol;
#pragma unroll
        for (int r = 0; r < 4; ++r) {
          uint32 hv = bf16rne(o[r]);
          asm volatile("global_store_short %0, %1, off sc0"
                       :: "v"(hd + r * 1024), "v"(hv) : "memory");
        }
      }
      asm volatile("s_waitcnt vmcnt(0)" ::: "memory");  // h visible in L2
    }
    __syncthreads();  // B2

    if (tid == 0) {  // publish first (Y deferred)
      int val = t + 1;
      if (t >= 1)
        asm volatile("global_store_dword %0, %1, off sc0"
                     :: "v"(fastflag), "v"(val) : "memory");
      asm volatile("global_store_dword %0, %1, off sc0 sc1"
                   :: "v"(slowflag), "v"(val) : "memory");
    }

    // S3: wave0 reads back its own LLC flag; LDS-conflict burst per miss.
    if (wave == 0) {
      const int val = t + 1;
      for (int rb = 0; rb < 24; ++rb) {
        int v;
        asm volatile("global_load_dword %0, %1, off sc0 sc1\n\ts_waitcnt vmcnt(0)"
                     : "=v"(v) : "v"(slowflag) : "memory");
        if (__all(v >= val)) break;
        volatile float* lb = ((float*)part) + lane * 32;  // all lanes -> bank 0
        float s = 0.f;
#pragma unroll
        for (int k = 0; k < 8; ++k) s += lb[k];
        asm volatile("" :: "v"(s));
        VBURN(sb0, sb1, sb2, sb3, sbk);
      }
    }

    if (fin && isL1 && lq < 2) {  // deferred Y stores (off serial chain)
      float* yd = Y + ((size_t)t * 64 + xcd * 8 + lq * 4) * 1024 + fcol;
#pragma unroll
      for (int r = 0; r < 4; ++r) yd[r * 1024] = o[r];
    }
  }
  asm volatile("" :: "v"(junk), "v"(sb0), "v"(sb1), "v"(sb2), "v"(sb3));
}

extern "C" void kernel_launch(void* const* d_in, const int* in_sizes, int n_in,
                              void* d_out, int out_size, void* d_ws, size_t ws_size,
                              hipStream_t stream) {
  const float* Xt = (const float*)d_in[0];
  const float* W0 = (const float*)d_in[1];
  const float* b0 = (const float*)d_in[2];
  const float* W1 = (const float*)d_in[3];
  const float* b1 = (const float*)d_in[4];
  float* Y = (float*)d_out;

  int* cnt = (int*)d_ws;
  ushort_t* hbuf = (ushort_t*)((char*)d_ws + 40960);       // 640 KB h-state
  // S2 burn region: 64 MB at +1 MB, only if workspace is large enough.
  char* burnR = (ws_size >= ((size_t)65 << 20)) ? ((char*)d_ws + (1 << 20))
                                                : (char*)0;

  rnn_init<<<1, 256, 0, stream>>>(cnt);
  rnn_main<<<256, 512, 0, stream>>>(Xt, W0, b0, W1, b1, Y, hbuf, cnt, burnR);
}